// Round 3
// baseline (182.799 us; speedup 1.0000x reference)
//
#include <hip/hip_runtime.h>
#include <hip/hip_bf16.h>
#include <math.h>

// Problem constants (from reference)
#define BB 4
#define NN 256
#define FF 256
#define NF 192
#define NBLK (BB*NN)                 // 1024 (b,i) blocks
#define MTOT 262144.0f               // B*N*N samples per channel for BN stats

typedef unsigned short u16;
typedef unsigned int   u32;
typedef __attribute__((ext_vector_type(8))) short bf16x8;  // 8 bf16 = 4 VGPRs (MFMA A/B frag)
typedef __attribute__((ext_vector_type(4))) float f32x4;   // MFMA C/D frag

// ---- workspace layout (bytes) ----
// w1 packed bf16 in B-fragment order: [fchunk(32)][c(192)][8 f] = 98304 B
#define W1P_OFF 0
// per-channel BN affine {A, D} as float2: 1536 B
#define AD_OFF  98304
// per-block channel partials: sums at [c][blk], sumsq at [192+c][blk]: 1572864 B
#define P_OFF   102400
// total ws: ~1.7 MB (no h materialization)

__device__ __forceinline__ u32 pk2(float a, float b) {
    u32 r;
    asm("v_cvt_pk_bf16_f32 %0, %1, %2" : "=v"(r) : "v"(a), "v"(b));
    return r;  // low16 = bf16(a), high16 = bf16(b)
}

__device__ __forceinline__ u16 f2bf(float f) {  // RNE, cold path only
    u32 u = __float_as_uint(f);
    return (u16)((u + 0x7FFFu + ((u >> 16) & 1u)) >> 16);
}

// ---- K0: pack w1 [F][NF] fp32 -> bf16 blocks [fc][c][e], f = fc*8+e ----
__global__ void k0_pack_w1(const float* __restrict__ w1, u16* __restrict__ w1p) {
    int idx = blockIdx.x * 256 + threadIdx.x;        // 0..49151
    int e  = idx & 7;
    int c  = (idx >> 3) % NF;
    int fc = idx / (NF * 8);
    w1p[idx] = f2bf(w1[(fc * 8 + e) * NF + c]);
}

// =====================================================================
// Shared GEMM core (duplicated in k1a / k1b):
// block = (b, i), 512 threads = 8 waves; wave tile = 64 j x 96 c; K=256
// in 8 slices of 32. diff = |x_i - x_j| generated to LDS as bf16.
// LDS swizzle: chunk ^= (row>>1)&3  (2-bit XOR, period 8 rows).
//   Row stride = 16 words, so row*16 mod 32 alternates {0,16}; the 2-bit
//   chunk rotation makes every 8-lane phase of BOTH ds_write_b128 and
//   ds_read_b128 cover all 32 banks exactly once (slot-enumerated).
// Lane layout after MFMA (m89-verified C/D map):
//   j = jw + a*16 + (l>>4)*4 + r,  c = cw + n*16 + (l&15)
// =====================================================================

// ---- K1a: GEMM -> per-channel sum / sumsq partials (no h store) ----
__global__ __launch_bounds__(512, 2) void k1a_stats_gemm(
    const float* __restrict__ x, const u16* __restrict__ w1p,
    float* __restrict__ partials) {

    __shared__ float sxi[FF];              // 1 KB: x[b,i,:]
    __shared__ uint4 sdiff[NN * 4];        // 16 KB: diff tile [j][4 chunks of 8 bf16]
    __shared__ float sstat[8][96][2];      // 6 KB: per-wave channel partials

    const int bid = blockIdx.x;
    const int b = bid >> 8, i = bid & 255;
    const int t = threadIdx.x;
    const int w = t >> 6, l = t & 63;
    const int l15 = l & 15, lg = l >> 4;

    if (t < 256) sxi[t] = x[((size_t)b * NN + i) * FF + t];

    const int jw = (w >> 1) * 64;          // wave's j block (4 waves over j)
    const int cw = (w & 1) * 96;           // wave's c block (2 waves over c)

    const int jrow = t >> 1;
    const int fh = t & 1;
    const float* xpt = x + (((size_t)b * NN + jrow) * FF + fh * 16);
    const int swz = (jrow >> 1) & 3;       // 2-bit XOR swizzle
    const int sdw0 = jrow * 4 + ((fh * 2)     ^ swz);
    const int sdw1 = jrow * 4 + ((fh * 2 + 1) ^ swz);

    const int arow = jw + l15;
    const int aoff0 = arow * 4 + (lg ^ ((arow >> 1) & 3));
    const int bbase = lg * NF + cw + l15;

    f32x4 acc[4][6];
    #pragma unroll
    for (int a = 0; a < 4; a++)
        #pragma unroll
        for (int n = 0; n < 6; n++)
            acc[a][n] = (f32x4){0.f, 0.f, 0.f, 0.f};

    const bf16x8* w1p8 = (const bf16x8*)w1p;

    for (int kk = 0; kk < 8; ++kk) {       // K slices of 32
        __syncthreads();
        const float4* xp4 = (const float4*)(xpt + kk * 32);
        float4 x0 = xp4[0], x1 = xp4[1], x2 = xp4[2], x3 = xp4[3];
        const float4* xi4 = (const float4*)(sxi + kk * 32 + fh * 16);
        float4 i0 = xi4[0], i1 = xi4[1], i2 = xi4[2], i3 = xi4[3];
        u32 q0 = pk2(fabsf(x0.x - i0.x), fabsf(x0.y - i0.y));
        u32 q1 = pk2(fabsf(x0.z - i0.z), fabsf(x0.w - i0.w));
        u32 q2 = pk2(fabsf(x1.x - i1.x), fabsf(x1.y - i1.y));
        u32 q3 = pk2(fabsf(x1.z - i1.z), fabsf(x1.w - i1.w));
        u32 q4 = pk2(fabsf(x2.x - i2.x), fabsf(x2.y - i2.y));
        u32 q5 = pk2(fabsf(x2.z - i2.z), fabsf(x2.w - i2.w));
        u32 q6 = pk2(fabsf(x3.x - i3.x), fabsf(x3.y - i3.y));
        u32 q7 = pk2(fabsf(x3.z - i3.z), fabsf(x3.w - i3.w));
        sdiff[sdw0] = make_uint4(q0, q1, q2, q3);
        sdiff[sdw1] = make_uint4(q4, q5, q6, q7);
        __syncthreads();

        bf16x8 bfr[6];
        #pragma unroll
        for (int n = 0; n < 6; n++) bfr[n] = w1p8[kk * 768 + bbase + n * 16];
        bf16x8 afr[4];
        #pragma unroll
        for (int a = 0; a < 4; a++) afr[a] = *(const bf16x8*)&sdiff[aoff0 + a * 64];
        #pragma unroll
        for (int a = 0; a < 4; a++)
            #pragma unroll
            for (int n = 0; n < 6; n++)
                acc[a][n] = __builtin_amdgcn_mfma_f32_16x16x32_bf16(afr[a], bfr[n], acc[a][n], 0, 0, 0);
    }

    // ---- per-channel partial sums (BN stats), deterministic ----
    float ps[6], pq[6];
    #pragma unroll
    for (int n = 0; n < 6; n++) {
        float s = 0.f, q = 0.f;
        #pragma unroll
        for (int a = 0; a < 4; a++) {
            f32x4 v = acc[a][n];
            s += v.x + v.y + v.z + v.w;
            q += v.x * v.x + v.y * v.y + v.z * v.z + v.w * v.w;
        }
        s += __shfl_xor(s, 16); s += __shfl_xor(s, 32);
        q += __shfl_xor(q, 16); q += __shfl_xor(q, 32);
        ps[n] = s; pq[n] = q;
    }
    if (l < 16) {
        #pragma unroll
        for (int n = 0; n < 6; n++) {
            sstat[w][n * 16 + l][0] = ps[n];
            sstat[w][n * 16 + l][1] = pq[n];
        }
    }
    __syncthreads();
    if (t < NF) {
        const int ch = t % 96, hs = t / 96;   // c = hs*96 + ch = t
        float S = 0.f, Q = 0.f;
        for (int ww = hs; ww < 8; ww += 2) { S += sstat[ww][ch][0]; Q += sstat[ww][ch][1]; }
        partials[(size_t)t * NBLK + bid]        = S;
        partials[(size_t)(NF + t) * NBLK + bid] = Q;
    }
}

// ---- K2: reduce partials -> per-channel A = gamma*rsqrt(var+eps), D = beta - mean*A ----
__global__ void k2_stats(const float* __restrict__ partials,
                         const float* __restrict__ gamma, const float* __restrict__ beta,
                         float2* __restrict__ ad) {
    __shared__ float red[4][2];
    const int c = blockIdx.x;
    const int t = threadIdx.x;
    float S = 0.f, Q = 0.f;
    #pragma unroll
    for (int r = 0; r < 4; ++r) {
        const int blk = t + r * 256;
        S += partials[(size_t)c * NBLK + blk];
        Q += partials[(size_t)(NF + c) * NBLK + blk];
    }
    #pragma unroll
    for (int off = 1; off < 64; off <<= 1) { S += __shfl_xor(S, off); Q += __shfl_xor(Q, off); }
    if ((t & 63) == 0) { red[t >> 6][0] = S; red[t >> 6][1] = Q; }
    __syncthreads();
    if (t == 0) {
        S = red[0][0] + red[1][0] + red[2][0] + red[3][0];
        Q = red[0][1] + red[1][1] + red[2][1] + red[3][1];
        const float mean = S / MTOT;
        const float var  = Q / MTOT - mean * mean;
        const float rs   = 1.0f / sqrtf(var + 1e-5f);
        const float A = gamma[c] * rs;
        const float D = beta[c] - mean * A;
        ad[c] = make_float2(A, D);
    }
}

// ---- K1b: GEMM -> BN -> lrelu -> w2 -> row softmax -> out = eye - A ----
__global__ __launch_bounds__(512, 2) void k1b_score_gemm(
    const float* __restrict__ x, const u16* __restrict__ w1p,
    const float2* __restrict__ ad, const float* __restrict__ w2,
    float* __restrict__ out) {

    __shared__ float sxi[FF];              // 1 KB
    __shared__ uint4 sdiff[NN * 4];        // 16 KB
    __shared__ float sA[NF], sD[NF], sW2[NF];  // 2.25 KB BN affine + w2
    __shared__ float sS[2][NN];            // 2 KB: per-c-half row scores
    __shared__ float sredA[8], sredB[8];

    const int bid = blockIdx.x;
    const int b = bid >> 8, i = bid & 255;
    const int t = threadIdx.x;
    const int w = t >> 6, l = t & 63;
    const int l15 = l & 15, lg = l >> 4;

    if (t < 256) sxi[t] = x[((size_t)b * NN + i) * FF + t];
    if (t >= 256 && t < 256 + NF) {
        const int c = t - 256;
        const float2 v = ad[c];
        sA[c] = v.x; sD[c] = v.y; sW2[c] = w2[c];
    }

    const int jw = (w >> 1) * 64;
    const int cw = (w & 1) * 96;

    const int jrow = t >> 1;
    const int fh = t & 1;
    const float* xpt = x + (((size_t)b * NN + jrow) * FF + fh * 16);
    const int swz = (jrow >> 1) & 3;       // 2-bit XOR swizzle
    const int sdw0 = jrow * 4 + ((fh * 2)     ^ swz);
    const int sdw1 = jrow * 4 + ((fh * 2 + 1) ^ swz);

    const int arow = jw + l15;
    const int aoff0 = arow * 4 + (lg ^ ((arow >> 1) & 3));
    const int bbase = lg * NF + cw + l15;

    f32x4 acc[4][6];
    #pragma unroll
    for (int a = 0; a < 4; a++)
        #pragma unroll
        for (int n = 0; n < 6; n++)
            acc[a][n] = (f32x4){0.f, 0.f, 0.f, 0.f};

    const bf16x8* w1p8 = (const bf16x8*)w1p;

    for (int kk = 0; kk < 8; ++kk) {
        __syncthreads();
        const float4* xp4 = (const float4*)(xpt + kk * 32);
        float4 x0 = xp4[0], x1 = xp4[1], x2 = xp4[2], x3 = xp4[3];
        const float4* xi4 = (const float4*)(sxi + kk * 32 + fh * 16);
        float4 i0 = xi4[0], i1 = xi4[1], i2 = xi4[2], i3 = xi4[3];
        u32 q0 = pk2(fabsf(x0.x - i0.x), fabsf(x0.y - i0.y));
        u32 q1 = pk2(fabsf(x0.z - i0.z), fabsf(x0.w - i0.w));
        u32 q2 = pk2(fabsf(x1.x - i1.x), fabsf(x1.y - i1.y));
        u32 q3 = pk2(fabsf(x1.z - i1.z), fabsf(x1.w - i1.w));
        u32 q4 = pk2(fabsf(x2.x - i2.x), fabsf(x2.y - i2.y));
        u32 q5 = pk2(fabsf(x2.z - i2.z), fabsf(x2.w - i2.w));
        u32 q6 = pk2(fabsf(x3.x - i3.x), fabsf(x3.y - i3.y));
        u32 q7 = pk2(fabsf(x3.z - i3.z), fabsf(x3.w - i3.w));
        sdiff[sdw0] = make_uint4(q0, q1, q2, q3);
        sdiff[sdw1] = make_uint4(q4, q5, q6, q7);
        __syncthreads();

        bf16x8 bfr[6];
        #pragma unroll
        for (int n = 0; n < 6; n++) bfr[n] = w1p8[kk * 768 + bbase + n * 16];
        bf16x8 afr[4];
        #pragma unroll
        for (int a = 0; a < 4; a++) afr[a] = *(const bf16x8*)&sdiff[aoff0 + a * 64];
        #pragma unroll
        for (int a = 0; a < 4; a++)
            #pragma unroll
            for (int n = 0; n < 6; n++)
                acc[a][n] = __builtin_amdgcn_mfma_f32_16x16x32_bf16(afr[a], bfr[n], acc[a][n], 0, 0, 0);
    }

    // ---- epilogue: BN + leaky-relu + w2 contraction, in-register ----
    float sj[4][4];
    #pragma unroll
    for (int a = 0; a < 4; a++)
        #pragma unroll
        for (int r = 0; r < 4; r++) sj[a][r] = 0.f;

    #pragma unroll
    for (int n = 0; n < 6; n++) {
        const int c = cw + n * 16 + l15;
        const float A = sA[c], D = sD[c], W = sW2[c];
        #pragma unroll
        for (int a = 0; a < 4; a++) {
            const f32x4 v = acc[a][n];
            float z;
            z = fmaf(v.x, A, D); sj[a][0] += fmaxf(z, 0.01f * z) * W;
            z = fmaf(v.y, A, D); sj[a][1] += fmaxf(z, 0.01f * z) * W;
            z = fmaf(v.z, A, D); sj[a][2] += fmaxf(z, 0.01f * z) * W;
            z = fmaf(v.w, A, D); sj[a][3] += fmaxf(z, 0.01f * z) * W;
        }
    }
    // reduce over the 16-lane c-group (lanes sharing lg hold same j)
    #pragma unroll
    for (int a = 0; a < 4; a++)
        #pragma unroll
        for (int r = 0; r < 4; r++) {
            float v = sj[a][r];
            v += __shfl_xor(v, 1); v += __shfl_xor(v, 2);
            v += __shfl_xor(v, 4); v += __shfl_xor(v, 8);
            if (l15 == 0) sS[w & 1][jw + a * 16 + (lg << 2) + r] = v;
        }
    __syncthreads();

    // ---- row softmax over j (scores in sS), then out = eye - softmax ----
    float s = -3.0e38f;
    if (t < NN) {
        s = sS[0][t] + sS[1][t];
        if (t == i) s -= 1e8f;             // self-edge mask (ref semantics)
    }
    float m = s;
    #pragma unroll
    for (int off = 1; off < 64; off <<= 1) m = fmaxf(m, __shfl_xor(m, off));
    if (l == 0) sredA[w] = m;
    __syncthreads();
    m = fmaxf(fmaxf(sredA[0], sredA[1]), fmaxf(sredA[2], sredA[3]));
    float e = 0.f;
    if (t < NN) e = expf(s - m);           // exp(-1e8 - m) underflows to exact 0
    float q = e;
    #pragma unroll
    for (int off = 1; off < 64; off <<= 1) q += __shfl_xor(q, off);
    if (l == 0) sredB[w] = q;
    __syncthreads();
    if (t < NN) {
        const float inv = 1.0f / (sredB[0] + sredB[1] + sredB[2] + sredB[3]);
        out[(size_t)bid * NN + t] = (t == i ? 1.0f : 0.0f) - e * inv;
    }
}

extern "C" void kernel_launch(void* const* d_in, const int* in_sizes, int n_in,
                              void* d_out, int out_size, void* d_ws, size_t ws_size,
                              hipStream_t stream) {
    const float* x     = (const float*)d_in[0];
    // d_in[1] = W_id (identity by construction) -- unused
    const float* w1    = (const float*)d_in[2];
    // d_in[3] = b1 -- cancels in BN mean subtraction; unused
    const float* gamma = (const float*)d_in[4];
    const float* beta  = (const float*)d_in[5];
    const float* w2    = (const float*)d_in[6];
    // d_in[7] = b2 -- cancels in row softmax; unused

    char* ws = (char*)d_ws;
    u16*    w1p      = (u16*)(ws + W1P_OFF);
    float2* ad       = (float2*)(ws + AD_OFF);
    float*  partials = (float*)(ws + P_OFF);
    float*  out      = (float*)d_out;

    k0_pack_w1    <<<dim3(192),  dim3(256), 0, stream>>>(w1, w1p);
    k1a_stats_gemm<<<dim3(NBLK), dim3(512), 0, stream>>>(x, w1p, partials);
    k2_stats      <<<dim3(NF),   dim3(256), 0, stream>>>(partials, gamma, beta, ad);
    k1b_score_gemm<<<dim3(NBLK), dim3(512), 0, stream>>>(x, w1p, ad, w2, out);
}

// Round 6
// 133.702 us; speedup vs baseline: 1.3672x; 1.3672x over previous
//
#include <hip/hip_runtime.h>
#include <hip/hip_bf16.h>
#include <math.h>

// Problem constants (from reference)
#define BB 4
#define NN 256
#define FF 256
#define NF 192
#define MTOT 262144.0f               // B*N*N samples per channel for BN stats
#define NB2 2560                     // triangular quarter-blocks per GEMM pass (4b x 640)

typedef unsigned short u16;
typedef unsigned int   u32;
typedef __attribute__((ext_vector_type(8))) short bf16x8;  // 8 bf16 = 4 VGPRs (MFMA A/B frag)
typedef __attribute__((ext_vector_type(4))) float f32x4;   // MFMA C/D frag

// ---- workspace layout (bytes) ----
#define W1P_OFF 0                    // w1 packed bf16 [fc(32)][c(192)][8]: 98304 B
#define AD_OFF  98304                // per-channel {A,D} float2: 1536 B
#define P_OFF   99840                // partials: S at [c][NB2], Q at [192+c][NB2]: 3.93 MB
// total ws: ~4.03 MB

__device__ __forceinline__ u32 pk2(float a, float b) {
    u32 r;
    asm("v_cvt_pk_bf16_f32 %0, %1, %2" : "=v"(r) : "v"(a), "v"(b));
    return r;  // low16 = bf16(a), high16 = bf16(b)
}

__device__ __forceinline__ u16 f2bf(float f) {  // RNE, cold path only
    u32 u = __float_as_uint(f);
    return (u16)((u + 0x7FFFu + ((u >> 16) & 1u)) >> 16);
}

// ---- K0: pack w1 [F][NF] fp32 -> bf16 blocks [fc][c][e], f = fc*8+e ----
__global__ void k0_pack_w1(const float* __restrict__ w1, u16* __restrict__ w1p) {
    int idx = blockIdx.x * 256 + threadIdx.x;        // 0..49151
    int e  = idx & 7;
    int c  = (idx >> 3) % NF;
    int fc = idx / (NF * 8);
    w1p[idx] = f2bf(w1[(fc * 8 + e) * NF + c]);
}

// ---- blockIdx -> (b, i, qj) for the triangular quarter grid ----
// per b: 640 pairs, segments by qi: [0,256):qi=0, [256,448):1, [448,576):2, [576,640):3
__device__ __forceinline__ void block_map(int bid, int& b, int& i, int& qj) {
    b = bid / 640;
    int r = bid % 640;
    int q, rr;
    if      (r < 256) { q = 0; rr = r; }
    else if (r < 448) { q = 1; rr = r - 256; }
    else if (r < 576) { q = 2; rr = r - 448; }
    else              { q = 3; rr = r - 576; }
    const int per = 4 - q;
    i  = q * 64 + rr / per;
    qj = q + rr % per;
}

// =====================================================================
// GEMM core: block = (b, i, qj); 256 threads = 4 waves.
// Output tile: 64 j (quarter qj) x 192 c. Wave tile 32j x 96c -> 12 acc
// frags (48 AGPR). K=256 in 8 slices of 32, double-buffered diff tile in
// LDS, ONE barrier per slice (hazards proven: reads of buf[p] at iter k
// are lgkm-drained at the iter-k+1 barrier, before buf[p] is rewritten).
// diff tile: [64 rows][4 uint4 chunks], swizzle chunk ^= (row>>1)&3:
// write (4 thr/row) and read (A-frag) phases both cover all 32 banks
// <=2-way (slot-enumerated).  Fragment maps HW-validated in round 3.
// =====================================================================
__device__ __forceinline__ void diff_write(uint4* sd, int wbase, int widx,
        float4 a0, float4 a1, const float* sxi, int koff, int chunk) {
    const float4 i0 = *(const float4*)(sxi + koff + chunk * 8);
    const float4 i1 = *(const float4*)(sxi + koff + chunk * 8 + 4);
    uint4 v;
    v.x = pk2(fabsf(a0.x - i0.x), fabsf(a0.y - i0.y));
    v.y = pk2(fabsf(a0.z - i0.z), fabsf(a0.w - i0.w));
    v.z = pk2(fabsf(a1.x - i1.x), fabsf(a1.y - i1.y));
    v.w = pk2(fabsf(a1.z - i1.z), fabsf(a1.w - i1.w));
    sd[wbase + widx] = v;
}

__device__ __forceinline__ void gemm_core(const float* __restrict__ x,
        const u16* __restrict__ w1p, int b, int i, int qj, int t,
        float* sxi, uint4* sd, f32x4 acc[2][6]) {
    const int l = t & 63, l15 = l & 15, lg = l >> 4, w = t >> 6;
    const int jw = (w >> 1) * 32;          // wave j-chunk (2 x 32)
    const int cw = (w & 1) * 96;           // wave c-chunk (2 x 96)
    const int jrow = t >> 2, chunk = t & 3;
    const int jglob = qj * 64 + jrow;
    const float* xpt = x + (size_t)(b * NN + jglob) * FF;
    const int widx = jrow * 4 + (chunk ^ ((jrow >> 1) & 3));
    int aidx[2];
    #pragma unroll
    for (int a = 0; a < 2; a++) {
        const int row = jw + a * 16 + l15;
        aidx[a] = row * 4 + (lg ^ ((row >> 1) & 3));
    }
    const int bbase = lg * NF + cw + l15;
    const bf16x8* w1p8 = (const bf16x8*)w1p;

    sxi[t] = x[(size_t)(b * NN + i) * FF + t];
    float4 xa = *(const float4*)(xpt + chunk * 8);
    float4 xb = *(const float4*)(xpt + chunk * 8 + 4);
    __syncthreads();                       // sxi ready
    diff_write(sd, 0, widx, xa, xb, sxi, 0, chunk);

    #pragma unroll
    for (int a = 0; a < 2; a++)
        #pragma unroll
        for (int n = 0; n < 6; n++) acc[a][n] = (f32x4){0.f, 0.f, 0.f, 0.f};

    for (int kk = 0; kk < 8; ++kk) {
        __syncthreads();                   // sd[kk&1] ready
        float4 na, nb;
        if (kk < 7) {                      // prefetch next slice (issued post-barrier,
            na = *(const float4*)(xpt + (kk + 1) * 32 + chunk * 8);       // consumed at tail
            nb = *(const float4*)(xpt + (kk + 1) * 32 + chunk * 8 + 4);   // -> hidden by MFMA)
        }
        const int rb = (kk & 1) * 256;
        bf16x8 bfr[6];
        #pragma unroll
        for (int n = 0; n < 6; n++) bfr[n] = w1p8[kk * 768 + bbase + n * 16];
        bf16x8 afr[2];
        #pragma unroll
        for (int a = 0; a < 2; a++) afr[a] = *(const bf16x8*)&sd[rb + aidx[a]];
        #pragma unroll
        for (int a = 0; a < 2; a++)
            #pragma unroll
            for (int n = 0; n < 6; n++)
                acc[a][n] = __builtin_amdgcn_mfma_f32_16x16x32_bf16(afr[a], bfr[n], acc[a][n], 0, 0, 0);
        if (kk < 7)
            diff_write(sd, ((kk + 1) & 1) * 256, widx, na, nb, sxi, (kk + 1) * 32, chunk);
    }
}

// ---- K1a: triangular GEMM -> weighted per-channel sum/sumsq partials ----
__global__ __launch_bounds__(256, 4) void k1a_stats_gemm(
    const float* __restrict__ x, const u16* __restrict__ w1p,
    float* __restrict__ partials) {

    __shared__ float sxi[FF];              // 1 KB
    __shared__ uint4 sd[2 * 256];          // 8 KB dbuf diff tile
    __shared__ float sstat[4][96][2];      // 3 KB

    int b, i, qj;
    block_map(blockIdx.x, b, i, qj);
    const int t = threadIdx.x;
    const int l = t & 63, l15 = l & 15, w = t >> 6;

    f32x4 acc[2][6];
    gemm_core(x, w1p, b, i, qj, t, sxi, sd, acc);

    // lane: j = jw + a*16 + (l>>4)*4 + r, c = cw + n*16 + l15 (HW-validated map)
    float ps[6], pq[6];
    #pragma unroll
    for (int n = 0; n < 6; n++) {
        float s = 0.f, q = 0.f;
        #pragma unroll
        for (int a = 0; a < 2; a++) {
            const f32x4 v = acc[a][n];
            s += v.x + v.y + v.z + v.w;
            q += v.x * v.x + v.y * v.y + v.z * v.z + v.w * v.w;
        }
        s += __shfl_xor(s, 16); s += __shfl_xor(s, 32);   // sum over lg (j sub-rows)
        q += __shfl_xor(q, 16); q += __shfl_xor(q, 32);
        ps[n] = s; pq[n] = q;
    }
    if (l < 16) {
        #pragma unroll
        for (int n = 0; n < 6; n++) {
            sstat[w][n * 16 + l15][0] = ps[n];
            sstat[w][n * 16 + l15][1] = pq[n];
        }
    }
    __syncthreads();
    if (t < NF) {
        const int ch = t / 96, cl = t % 96;               // waves {ch, ch+2} hold half ch
        float S = sstat[ch][cl][0] + sstat[ch + 2][cl][0];
        float Q = sstat[ch][cl][1] + sstat[ch + 2][cl][1];
        const float W = (qj > (i >> 6)) ? 2.0f : 1.0f;    // mirror weight (diag quarter = 1)
        partials[(size_t)t * NB2 + blockIdx.x]        = S * W;
        partials[(size_t)(NF + t) * NB2 + blockIdx.x] = Q * W;
    }
}

// ---- K2: reduce partials -> A = gamma*rsqrt(var+eps), D = beta - mean*A ----
__global__ void k2_stats(const float* __restrict__ partials,
                         const float* __restrict__ gamma, const float* __restrict__ beta,
                         float2* __restrict__ ad) {
    __shared__ float red[4][2];
    const int c = blockIdx.x;
    const int t = threadIdx.x;
    float S = 0.f, Q = 0.f;
    #pragma unroll
    for (int r = 0; r < 10; ++r) {
        const int blk = t + r * 256;                      // 10*256 = 2560 = NB2
        S += partials[(size_t)c * NB2 + blk];
        Q += partials[(size_t)(NF + c) * NB2 + blk];
    }
    #pragma unroll
    for (int off = 1; off < 64; off <<= 1) { S += __shfl_xor(S, off); Q += __shfl_xor(Q, off); }
    if ((t & 63) == 0) { red[t >> 6][0] = S; red[t >> 6][1] = Q; }
    __syncthreads();
    if (t == 0) {
        S = red[0][0] + red[1][0] + red[2][0] + red[3][0];
        Q = red[0][1] + red[1][1] + red[2][1] + red[3][1];
        const float mean = S / MTOT;
        const float var  = Q / MTOT - mean * mean;
        const float rs   = 1.0f / sqrtf(var + 1e-5f);
        const float A = gamma[c] * rs;
        const float D = beta[c] - mean * A;
        ad[c] = make_float2(A, D);
    }
}

// ---- K1b: triangular GEMM -> BN -> lrelu -> w2 -> raw scores (+mirror) ----
// scores staged in d_out; k3 rewrites in place.
__global__ __launch_bounds__(256, 4) void k1b_score_gemm(
    const float* __restrict__ x, const u16* __restrict__ w1p,
    const float2* __restrict__ ad, const float* __restrict__ w2,
    float* __restrict__ out) {

    __shared__ float sxi[FF];
    __shared__ uint4 sd[2 * 256];
    __shared__ float sA[NF], sD[NF], sW2[NF];
    __shared__ float sS[2][64];

    int b, i, qj;
    block_map(blockIdx.x, b, i, qj);
    const int t = threadIdx.x;
    const int l = t & 63, l15 = l & 15, lg = l >> 4, w = t >> 6;
    const int jw = (w >> 1) * 32, cw = (w & 1) * 96;

    if (t < NF) {
        const float2 v = ad[t];
        sA[t] = v.x; sD[t] = v.y; sW2[t] = w2[t];
    }

    f32x4 acc[2][6];
    gemm_core(x, w1p, b, i, qj, t, sxi, sd, acc);   // its first barrier covers sA/sD/sW2 too

    // epilogue: BN + leaky-relu + w2 contraction, in-register
    float sj[2][4];
    #pragma unroll
    for (int a = 0; a < 2; a++)
        #pragma unroll
        for (int r = 0; r < 4; r++) sj[a][r] = 0.f;
    #pragma unroll
    for (int n = 0; n < 6; n++) {
        const int c = cw + n * 16 + l15;
        const float A = sA[c], D = sD[c], W = sW2[c];
        #pragma unroll
        for (int a = 0; a < 2; a++) {
            const f32x4 v = acc[a][n];
            float z;
            z = fmaf(v.x, A, D); sj[a][0] += fmaxf(z, 0.01f * z) * W;
            z = fmaf(v.y, A, D); sj[a][1] += fmaxf(z, 0.01f * z) * W;
            z = fmaf(v.z, A, D); sj[a][2] += fmaxf(z, 0.01f * z) * W;
            z = fmaf(v.w, A, D); sj[a][3] += fmaxf(z, 0.01f * z) * W;
        }
    }
    #pragma unroll
    for (int a = 0; a < 2; a++)
        #pragma unroll
        for (int r = 0; r < 4; r++) {
            float v = sj[a][r];
            v += __shfl_xor(v, 1); v += __shfl_xor(v, 2);   // sum over 16 c-lanes
            v += __shfl_xor(v, 4); v += __shfl_xor(v, 8);
            if (l15 == 0) sS[w & 1][jw + a * 16 + (lg << 2) + r] = v;
        }
    __syncthreads();

    if (t < 64) {
        const float s = sS[0][t] + sS[1][t];
        const int jglob = qj * 64 + t;
        out[(size_t)(b * NN + i) * NN + jglob] = s;
        if (qj > (i >> 6))                                  // mirror (exactly-once coverage proven)
            out[(size_t)(b * NN + jglob) * NN + i] = s;
    }
}

// ---- K3: in-place row softmax on scores; out = eye - softmax ----
__global__ __launch_bounds__(256) void k3_softmax(float* __restrict__ out) {
    __shared__ float redA[4], redB[4];
    const int r = blockIdx.x, t = threadIdx.x, i = r & 255;
    float s = out[(size_t)r * NN + t];
    if (t == i) s -= 1e8f;                 // self-edge mask (ref semantics)
    float m = s;
    #pragma unroll
    for (int off = 1; off < 64; off <<= 1) m = fmaxf(m, __shfl_xor(m, off));
    if ((t & 63) == 0) redA[t >> 6] = m;
    __syncthreads();
    m = fmaxf(fmaxf(redA[0], redA[1]), fmaxf(redA[2], redA[3]));
    const float e = expf(s - m);           // exp(-1e8 - m) underflows to exact 0
    float q = e;
    #pragma unroll
    for (int off = 1; off < 64; off <<= 1) q += __shfl_xor(q, off);
    if ((t & 63) == 0) redB[t >> 6] = q;
    __syncthreads();
    const float inv = 1.0f / (redB[0] + redB[1] + redB[2] + redB[3]);
    out[(size_t)r * NN + t] = (t == i ? 1.0f : 0.0f) - e * inv;
}

extern "C" void kernel_launch(void* const* d_in, const int* in_sizes, int n_in,
                              void* d_out, int out_size, void* d_ws, size_t ws_size,
                              hipStream_t stream) {
    const float* x     = (const float*)d_in[0];
    // d_in[1] = W_id (identity by construction) -- unused
    const float* w1    = (const float*)d_in[2];
    // d_in[3] = b1 -- cancels in BN mean subtraction; unused
    const float* gamma = (const float*)d_in[4];
    const float* beta  = (const float*)d_in[5];
    const float* w2    = (const float*)d_in[6];
    // d_in[7] = b2 -- cancels in row softmax; unused

    char* ws = (char*)d_ws;
    u16*    w1p      = (u16*)(ws + W1P_OFF);
    float2* ad       = (float2*)(ws + AD_OFF);
    float*  partials = (float*)(ws + P_OFF);
    float*  out      = (float*)d_out;

    k0_pack_w1    <<<dim3(192),  dim3(256), 0, stream>>>(w1, w1p);
    k1a_stats_gemm<<<dim3(NB2),  dim3(256), 0, stream>>>(x, w1p, partials);
    k2_stats      <<<dim3(NF),   dim3(256), 0, stream>>>(partials, gamma, beta, ad);
    k1b_score_gemm<<<dim3(NB2),  dim3(256), 0, stream>>>(x, w1p, ad, w2, out);
    k3_softmax    <<<dim3(BB*NN), dim3(256), 0, stream>>>(out);
}

// Round 8
// 128.911 us; speedup vs baseline: 1.4180x; 1.0372x over previous
//
#include <hip/hip_runtime.h>
#include <hip/hip_bf16.h>
#include <math.h>

// Problem constants (from reference)
#define BB 4
#define NN 256
#define FF 256
#define NF 192
#define MTOT 262144.0f               // B*N*N samples per channel for BN stats
#define NB2 2560                     // triangular quarter-blocks per GEMM pass (4b x 640)

typedef unsigned short u16;
typedef unsigned int   u32;
typedef __attribute__((ext_vector_type(8))) short bf16x8;  // 8 bf16 = 4 VGPRs (MFMA A/B frag)
typedef __attribute__((ext_vector_type(4))) float f32x4;   // MFMA C/D frag

// ---- workspace layout (bytes) ----
#define W1P_OFF 0                    // w1 packed bf16 [fc(32)][c(192)][8]: 98304 B
#define AD_OFF  98304                // per-channel {A,D} float2: 1536 B
#define P_OFF   99840                // partials: S at [c][NB2], Q at [192+c][NB2]: 3.93 MB
// total ws: ~4.03 MB

__device__ __forceinline__ u32 pk2(float a, float b) {
    u32 r;
    asm("v_cvt_pk_bf16_f32 %0, %1, %2" : "=v"(r) : "v"(a), "v"(b));
    return r;  // low16 = bf16(a), high16 = bf16(b)
}

__device__ __forceinline__ u16 f2bf(float f) {  // RNE, cold path only
    u32 u = __float_as_uint(f);
    return (u16)((u + 0x7FFFu + ((u >> 16) & 1u)) >> 16);
}

// ---- K0: pack w1 [F][NF] fp32 -> bf16 blocks [fc][c][e], f = fc*8+e ----
__global__ void k0_pack_w1(const float* __restrict__ w1, u16* __restrict__ w1p) {
    int idx = blockIdx.x * 256 + threadIdx.x;        // 0..49151
    int e  = idx & 7;
    int c  = (idx >> 3) % NF;
    int fc = idx / (NF * 8);
    w1p[idx] = f2bf(w1[(fc * 8 + e) * NF + c]);
}

// ---- blockIdx -> (b, i, qj) for the triangular quarter grid ----
// per b: 640 pairs, segments by qi: [0,256):qi=0, [256,448):1, [448,576):2, [576,640):3
__device__ __forceinline__ void block_map(int bid, int& b, int& i, int& qj) {
    b = bid / 640;
    int r = bid % 640;
    int q, rr;
    if      (r < 256) { q = 0; rr = r; }
    else if (r < 448) { q = 1; rr = r - 256; }
    else if (r < 576) { q = 2; rr = r - 448; }
    else              { q = 3; rr = r - 576; }
    const int per = 4 - q;
    i  = q * 64 + rr / per;
    qj = q + rr % per;
}

// =====================================================================
// GEMM core: block = (b, i, qj); 256 threads = 4 waves.
// Output tile: 64 j (quarter qj) x 192 c. Wave tile 32j x 96c -> 12 acc
// frags (48 AGPR). K=256 in 8 slices of 32, double-buffered diff tile in
// LDS, ONE barrier per slice. B-fragments (w1p, L2-resident) are
// cross-slice prefetched REGISTER-NEUTRALLY: the n-loop reloads bcur[n]
// for slice kk+1 right after its last use in slice kk (slot dead after
// the 2 MFMAs reading it), so each reload has ~10 MFMAs + diff-gen +
// barrier (~150-250 cyc) of cover for the ~200cy L2 latency. The round-6
// bcur/bnxt form needed ~140+ regs > the 128 cap of launch_bounds(256,4)
// -> spill/de-schedule risk; this form stays ~111 regs.
// diff tile: [64 rows][4 uint4 chunks], swizzle chunk ^= (row>>1)&3:
// write and read phases both cover all 32 banks <=2-way (slot-enumerated).
// Fragment maps HW-validated in round 3.
// =====================================================================
__device__ __forceinline__ void diff_write(uint4* sd, int wbase, int widx,
        float4 a0, float4 a1, const float* sxi, int koff, int chunk) {
    const float4 i0 = *(const float4*)(sxi + koff + chunk * 8);
    const float4 i1 = *(const float4*)(sxi + koff + chunk * 8 + 4);
    uint4 v;
    v.x = pk2(fabsf(a0.x - i0.x), fabsf(a0.y - i0.y));
    v.y = pk2(fabsf(a0.z - i0.z), fabsf(a0.w - i0.w));
    v.z = pk2(fabsf(a1.x - i1.x), fabsf(a1.y - i1.y));
    v.w = pk2(fabsf(a1.z - i1.z), fabsf(a1.w - i1.w));
    sd[wbase + widx] = v;
}

__device__ __forceinline__ void gemm_core(const float* __restrict__ x,
        const u16* __restrict__ w1p, int b, int i, int qj, int t,
        float* sxi, uint4* sd, f32x4 acc[2][6]) {
    const int l = t & 63, l15 = l & 15, lg = l >> 4, w = t >> 6;
    const int jw = (w >> 1) * 32;          // wave j-chunk (2 x 32)
    const int cw = (w & 1) * 96;           // wave c-chunk (2 x 96)
    const int jrow = t >> 2, chunk = t & 3;
    const int jglob = qj * 64 + jrow;
    const float* xpt = x + (size_t)(b * NN + jglob) * FF;
    const int widx = jrow * 4 + (chunk ^ ((jrow >> 1) & 3));
    int aidx[2];
    #pragma unroll
    for (int a = 0; a < 2; a++) {
        const int row = jw + a * 16 + l15;
        aidx[a] = row * 4 + (lg ^ ((row >> 1) & 3));
    }
    const int bbase = lg * NF + cw + l15;
    const bf16x8* w1p8 = (const bf16x8*)w1p;

    sxi[t] = x[(size_t)(b * NN + i) * FF + t];
    float4 xa = *(const float4*)(xpt + chunk * 8);
    float4 xb = *(const float4*)(xpt + chunk * 8 + 4);
    bf16x8 bcur[6];                        // slice-0 B-frags: issued pre-barrier
    #pragma unroll
    for (int n = 0; n < 6; n++) bcur[n] = w1p8[bbase + n * 16];
    __syncthreads();                       // sxi ready
    diff_write(sd, 0, widx, xa, xb, sxi, 0, chunk);

    #pragma unroll
    for (int a = 0; a < 2; a++)
        #pragma unroll
        for (int n = 0; n < 6; n++) acc[a][n] = (f32x4){0.f, 0.f, 0.f, 0.f};

    for (int kk = 0; kk < 8; ++kk) {
        __syncthreads();                   // sd[kk&1] ready
        float4 na, nb;
        if (kk < 7) {                      // x-row prefetch for next slice
            na = *(const float4*)(xpt + (kk + 1) * 32 + chunk * 8);
            nb = *(const float4*)(xpt + (kk + 1) * 32 + chunk * 8 + 4);
        }
        const int rb = (kk & 1) * 256;
        bf16x8 afr[2];
        #pragma unroll
        for (int a = 0; a < 2; a++) afr[a] = *(const bf16x8*)&sd[rb + aidx[a]];
        #pragma unroll
        for (int n = 0; n < 6; n++) {
            acc[0][n] = __builtin_amdgcn_mfma_f32_16x16x32_bf16(afr[0], bcur[n], acc[0][n], 0, 0, 0);
            acc[1][n] = __builtin_amdgcn_mfma_f32_16x16x32_bf16(afr[1], bcur[n], acc[1][n], 0, 0, 0);
            if (kk < 7)                    // slot dead after the 2 MFMAs -> free reload
                bcur[n] = w1p8[(kk + 1) * 768 + bbase + n * 16];
        }
        if (kk < 7)
            diff_write(sd, ((kk + 1) & 1) * 256, widx, na, nb, sxi, (kk + 1) * 32, chunk);
    }
}

// ---- K1a: triangular GEMM -> weighted per-channel sum/sumsq partials ----
__global__ __launch_bounds__(256, 4) void k1a_stats_gemm(
    const float* __restrict__ x, const u16* __restrict__ w1p,
    float* __restrict__ partials) {

    __shared__ float sxi[FF];              // 1 KB
    __shared__ uint4 sd[2 * 256];          // 8 KB dbuf diff tile
    __shared__ float sstat[4][96][2];      // 3 KB

    int b, i, qj;
    block_map(blockIdx.x, b, i, qj);
    const int t = threadIdx.x;
    const int l = t & 63, l15 = l & 15, w = t >> 6;

    f32x4 acc[2][6];
    gemm_core(x, w1p, b, i, qj, t, sxi, sd, acc);

    // lane: j = jw + a*16 + (l>>4)*4 + r, c = cw + n*16 + l15 (HW-validated map)
    float ps[6], pq[6];
    #pragma unroll
    for (int n = 0; n < 6; n++) {
        float s = 0.f, q = 0.f;
        #pragma unroll
        for (int a = 0; a < 2; a++) {
            const f32x4 v = acc[a][n];
            s += v.x + v.y + v.z + v.w;
            q += v.x * v.x + v.y * v.y + v.z * v.z + v.w * v.w;
        }
        s += __shfl_xor(s, 16); s += __shfl_xor(s, 32);   // sum over lg (j sub-rows)
        q += __shfl_xor(q, 16); q += __shfl_xor(q, 32);
        ps[n] = s; pq[n] = q;
    }
    if (l < 16) {
        #pragma unroll
        for (int n = 0; n < 6; n++) {
            sstat[w][n * 16 + l15][0] = ps[n];
            sstat[w][n * 16 + l15][1] = pq[n];
        }
    }
    __syncthreads();
    if (t < NF) {
        const int ch = t / 96, cl = t % 96;               // waves {ch, ch+2} hold half ch
        float S = sstat[ch][cl][0] + sstat[ch + 2][cl][0];
        float Q = sstat[ch][cl][1] + sstat[ch + 2][cl][1];
        const float W = (qj > (i >> 6)) ? 2.0f : 1.0f;    // mirror weight (diag quarter = 1)
        partials[(size_t)t * NB2 + blockIdx.x]        = S * W;
        partials[(size_t)(NF + t) * NB2 + blockIdx.x] = Q * W;
    }
}

// ---- K2: reduce partials -> A = gamma*rsqrt(var+eps), D = beta - mean*A ----
__global__ void k2_stats(const float* __restrict__ partials,
                         const float* __restrict__ gamma, const float* __restrict__ beta,
                         float2* __restrict__ ad) {
    __shared__ float red[4][2];
    const int c = blockIdx.x;
    const int t = threadIdx.x;
    float S = 0.f, Q = 0.f;
    #pragma unroll
    for (int r = 0; r < 10; ++r) {
        const int blk = t + r * 256;                      // 10*256 = 2560 = NB2
        S += partials[(size_t)c * NB2 + blk];
        Q += partials[(size_t)(NF + c) * NB2 + blk];
    }
    #pragma unroll
    for (int off = 1; off < 64; off <<= 1) { S += __shfl_xor(S, off); Q += __shfl_xor(Q, off); }
    if ((t & 63) == 0) { red[t >> 6][0] = S; red[t >> 6][1] = Q; }
    __syncthreads();
    if (t == 0) {
        S = red[0][0] + red[1][0] + red[2][0] + red[3][0];
        Q = red[0][1] + red[1][1] + red[2][1] + red[3][1];
        const float mean = S / MTOT;
        const float var  = Q / MTOT - mean * mean;
        const float rs   = 1.0f / sqrtf(var + 1e-5f);
        const float A = gamma[c] * rs;
        const float D = beta[c] - mean * A;
        ad[c] = make_float2(A, D);
    }
}

// ---- K1b: triangular GEMM -> BN -> lrelu -> w2 -> raw scores (+mirror) ----
// scores staged in d_out; k3 rewrites in place.
__global__ __launch_bounds__(256, 4) void k1b_score_gemm(
    const float* __restrict__ x, const u16* __restrict__ w1p,
    const float2* __restrict__ ad, const float* __restrict__ w2,
    float* __restrict__ out) {

    __shared__ float sxi[FF];
    __shared__ uint4 sd[2 * 256];
    __shared__ float sA[NF], sD[NF], sW2[NF];
    __shared__ float sS[2][64];

    int b, i, qj;
    block_map(blockIdx.x, b, i, qj);
    const int t = threadIdx.x;
    const int l = t & 63, l15 = l & 15, lg = l >> 4, w = t >> 6;
    const int jw = (w >> 1) * 32, cw = (w & 1) * 96;

    if (t < NF) {
        const float2 v = ad[t];
        sA[t] = v.x; sD[t] = v.y; sW2[t] = w2[t];
    }

    f32x4 acc[2][6];
    gemm_core(x, w1p, b, i, qj, t, sxi, sd, acc);   // its first barrier covers sA/sD/sW2 too

    // epilogue: BN + leaky-relu + w2 contraction, in-register
    float sj[2][4];
    #pragma unroll
    for (int a = 0; a < 2; a++)
        #pragma unroll
        for (int r = 0; r < 4; r++) sj[a][r] = 0.f;
    #pragma unroll
    for (int n = 0; n < 6; n++) {
        const int c = cw + n * 16 + l15;
        const float A = sA[c], D = sD[c], W = sW2[c];
        #pragma unroll
        for (int a = 0; a < 2; a++) {
            const f32x4 v = acc[a][n];
            float z;
            z = fmaf(v.x, A, D); sj[a][0] += fmaxf(z, 0.01f * z) * W;
            z = fmaf(v.y, A, D); sj[a][1] += fmaxf(z, 0.01f * z) * W;
            z = fmaf(v.z, A, D); sj[a][2] += fmaxf(z, 0.01f * z) * W;
            z = fmaf(v.w, A, D); sj[a][3] += fmaxf(z, 0.01f * z) * W;
        }
    }
    #pragma unroll
    for (int a = 0; a < 2; a++)
        #pragma unroll
        for (int r = 0; r < 4; r++) {
            float v = sj[a][r];
            v += __shfl_xor(v, 1); v += __shfl_xor(v, 2);   // sum over 16 c-lanes
            v += __shfl_xor(v, 4); v += __shfl_xor(v, 8);
            if (l15 == 0) sS[w & 1][jw + a * 16 + (lg << 2) + r] = v;
        }
    __syncthreads();

    if (t < 64) {
        const float s = sS[0][t] + sS[1][t];
        const int jglob = qj * 64 + t;
        out[(size_t)(b * NN + i) * NN + jglob] = s;
        if (qj > (i >> 6))                                  // mirror (exactly-once coverage proven)
            out[(size_t)(b * NN + jglob) * NN + i] = s;
    }
}

// ---- K3: in-place row softmax on scores; out = eye - softmax ----
__global__ __launch_bounds__(256) void k3_softmax(float* __restrict__ out) {
    __shared__ float redA[4], redB[4];
    const int r = blockIdx.x, t = threadIdx.x, i = r & 255;
    float s = out[(size_t)r * NN + t];
    if (t == i) s -= 1e8f;                 // self-edge mask (ref semantics)
    float m = s;
    #pragma unroll
    for (int off = 1; off < 64; off <<= 1) m = fmaxf(m, __shfl_xor(m, off));
    if ((t & 63) == 0) redA[t >> 6] = m;
    __syncthreads();
    m = fmaxf(fmaxf(redA[0], redA[1]), fmaxf(redA[2], redA[3]));
    const float e = expf(s - m);           // exp(-1e8 - m) underflows to exact 0
    float q = e;
    #pragma unroll
    for (int off = 1; off < 64; off <<= 1) q += __shfl_xor(q, off);
    if ((t & 63) == 0) redB[t >> 6] = q;
    __syncthreads();
    const float inv = 1.0f / (redB[0] + redB[1] + redB[2] + redB[3]);
    out[(size_t)r * NN + t] = (t == i ? 1.0f : 0.0f) - e * inv;
}

extern "C" void kernel_launch(void* const* d_in, const int* in_sizes, int n_in,
                              void* d_out, int out_size, void* d_ws, size_t ws_size,
                              hipStream_t stream) {
    const float* x     = (const float*)d_in[0];
    // d_in[1] = W_id (identity by construction) -- unused
    const float* w1    = (const float*)d_in[2];
    // d_in[3] = b1 -- cancels in BN mean subtraction; unused
    const float* gamma = (const float*)d_in[4];
    const float* beta  = (const float*)d_in[5];
    const float* w2    = (const float*)d_in[6];
    // d_in[7] = b2 -- cancels in row softmax; unused

    char* ws = (char*)d_ws;
    u16*    w1p      = (u16*)(ws + W1P_OFF);
    float2* ad       = (float2*)(ws + AD_OFF);
    float*  partials = (float*)(ws + P_OFF);
    float*  out      = (float*)d_out;

    k0_pack_w1    <<<dim3(192),  dim3(256), 0, stream>>>(w1, w1p);
    k1a_stats_gemm<<<dim3(NB2),  dim3(256), 0, stream>>>(x, w1p, partials);
    k2_stats      <<<dim3(NF),   dim3(256), 0, stream>>>(partials, gamma, beta, ad);
    k1b_score_gemm<<<dim3(NB2),  dim3(256), 0, stream>>>(x, w1p, ad, w2, out);
    k3_softmax    <<<dim3(BB*NN), dim3(256), 0, stream>>>(out);
}